// Round 8
// baseline (451.417 us; speedup 1.0000x reference)
//
#include <hip/hip_runtime.h>

#define EPSILON 1e-6f
#define NADMIN 256
#define NBATCH 16
#define NPIX (1024 * 1024)    // H*W per batch
#define BLK_X 64              // blocks per batch
#define THREADS 512
#define NCOPY 4               // LDS histogram copies (indexed by wave&3)
#define HSTRIDE 257
#define PX_PER_THREAD 8       // float4s per thread (= 32 px)
#define SCALE 65536.0f        // fixed-point scale (p in [0,1))

// d_ws layout: S u32[NBATCH*NADMIN] | cnt u32 | flag u32
#define SYNC_CNT (NBATCH * NADMIN)
#define SYNC_FLAG (NBATCH * NADMIN + 1)

// ---------------------------------------------------------------------------
// Pass 0: zero S + barrier state with plain stores (replay-safe).
// ---------------------------------------------------------------------------
__global__ __launch_bounds__(256) void zero_kernel(unsigned int* __restrict__ W)
{
    int i = blockIdx.x * blockDim.x + threadIdx.x;
    if (i < NBATCH * NADMIN + 2) W[i] = 0u;
}

// ---------------------------------------------------------------------------
// Fused segsum + apply. grid = (BLK_X, NBATCH) = 1024 blocks x 512 thr
// = exactly 4 blocks/CU; __launch_bounds__(512,8) caps VGPR at 64 so ALL
// blocks are co-resident -> grid barrier cannot deadlock.
// Phase 1: r7's integer LDS histogram (native ds_add_u32, 4 copies), with
//   per-thread P float4s HELD IN REGISTERS (32 VGPR) for phase 2.
//   Block partials flushed to global S via exact u32 atomics (deterministic).
// Barrier: arrive-counter + release-flag (zeroed each call by zero_kernel;
//   a rocprof solo-replay sees flag=1 and falls through -> no hang).
// Phase 2: coherent-read S, R in LDS, re-read ids (L2/L3-warm), write out
//   from register-held P. Saves apply's 67MB P re-read + reduce round-trip.
// ---------------------------------------------------------------------------
__global__ __launch_bounds__(THREADS, 8) void fused_kernel(
    const float* __restrict__ P,
    const int* __restrict__ ids,
    const float* __restrict__ census,
    unsigned int* __restrict__ W,     // S[4096] + cnt + flag
    float* __restrict__ out)
{
    __shared__ unsigned int hist[NCOPY * HSTRIDE];
    __shared__ float R_lds[NADMIN];

    const int b = blockIdx.y;
    const int t = threadIdx.x;

    for (int i = t; i < NCOPY * HSTRIDE; i += THREADS) hist[i] = 0u;
    __syncthreads();

    unsigned int* __restrict__ h = hist + ((t >> 6) & (NCOPY - 1)) * HSTRIDE;

    const float4* __restrict__ p4  = (const float4*)(P   + (size_t)b * NPIX);
    const int4*   __restrict__ id4 = (const int4*)  (ids + (size_t)b * NPIX);
    float4* __restrict__ o4 = (float4*)(out + (size_t)b * NPIX);

    const int i0 = blockIdx.x * THREADS + t;   // coalesced within block
    const int stride = BLK_X * THREADS;        // 32768 float4s

    // ---- Phase 1: histogram; keep P in registers ----
    float4 pr[PX_PER_THREAD];
    #pragma unroll
    for (int u = 0; u < PX_PER_THREAD; ++u) {
        pr[u] = p4[i0 + u * stride];
        int4 d = id4[i0 + u * stride];
        if (d.x >= 0) atomicAdd(&h[d.x], __float2uint_rn(pr[u].x * SCALE));
        if (d.y >= 0) atomicAdd(&h[d.y], __float2uint_rn(pr[u].y * SCALE));
        if (d.z >= 0) atomicAdd(&h[d.z], __float2uint_rn(pr[u].z * SCALE));
        if (d.w >= 0) atomicAdd(&h[d.w], __float2uint_rn(pr[u].w * SCALE));
    }
    __syncthreads();

    if (t < NADMIN) {
        unsigned int s = hist[t] + hist[HSTRIDE + t] +
                         hist[2 * HSTRIDE + t] + hist[3 * HSTRIDE + t];
        if (s) atomicAdd(&W[b * NADMIN + t], s);   // exact u32: deterministic
    }

    // ---- Grid barrier ----
    __threadfence();
    __syncthreads();
    if (t == 0) {
        unsigned int total = gridDim.x * gridDim.y;
        unsigned int old = atomicAdd(&W[SYNC_CNT], 1u);
        if (old == total - 1) atomicExch(&W[SYNC_FLAG], 1u);
        while (atomicAdd(&W[SYNC_FLAG], 0u) == 0u) {
            __builtin_amdgcn_s_sleep(8);
        }
    }
    __syncthreads();
    __threadfence();

    // ---- Phase 2: R in LDS, apply from register-held P ----
    if (t < NADMIN) {
        unsigned int sv = atomicAdd(&W[b * NADMIN + t], 0u);  // coherent read
        float S = (float)sv * (1.0f / SCALE);
        R_lds[t] = census[b * NADMIN + t] / (S + EPSILON);
    }
    __syncthreads();

    #pragma unroll
    for (int u = 0; u < PX_PER_THREAD; ++u) {
        int4 d = id4[i0 + u * stride];     // re-read ids (L2/L3-warm)
        float4 p = pr[u];
        float4 o;
        o.x = (d.x >= 0) ? p.x * R_lds[d.x] : p.x;
        o.y = (d.y >= 0) ? p.y * R_lds[d.y] : p.y;
        o.z = (d.z >= 0) ? p.z * R_lds[d.z] : p.z;
        o.w = (d.w >= 0) ? p.w * R_lds[d.w] : p.w;
        o4[i0 + u * stride] = o;
    }
}

extern "C" void kernel_launch(void* const* d_in, const int* in_sizes, int n_in,
                              void* d_out, int out_size, void* d_ws, size_t ws_size,
                              hipStream_t stream)
{
    const float* P      = (const float*)d_in[0];   // (B,1,H,W) f32
    const int*   ids    = (const int*)d_in[1];     // (B,H,W) i32
    const float* census = (const float*)d_in[2];   // (B,A) f32
    float* out = (float*)d_out;

    unsigned int* W = (unsigned int*)d_ws;         // S[4096] + cnt + flag

    zero_kernel<<<dim3((NBATCH * NADMIN + 2 + 255) / 256), dim3(256), 0, stream>>>(W);
    fused_kernel<<<dim3(BLK_X, NBATCH), dim3(THREADS), 0, stream>>>(P, ids, census, W, out);
}

// Round 9
// 75.002 us; speedup vs baseline: 6.0187x; 6.0187x over previous
//
#include <hip/hip_runtime.h>

#define EPSILON 1e-6f
#define NADMIN 256
#define NBATCH 16
#define NPIX (1024 * 1024)    // H*W per batch
#define SEG_BLOCKS 64         // segsum blocks per batch
#define SEG_THREADS 512
#define NCOPY 8               // histogram copies indexed by lane&7:
                              // kills WITHIN-INSTRUCTION same-address pairs
                              // (7.9 -> 0.9 expected per ds_add) — the r8
                              // post-mortem's discriminating hypothesis.
#define HSTRIDE 257           // odd stride: copies spread across banks
#define UNROLL 4
#define SCALE 65536.0f        // fixed-point scale (p in [0,1))

// ---------------------------------------------------------------------------
// Pass 1: per-batch partial segment sums in fixed-point u32 via native
// fire-and-forget ds_add_u32. Identical to round-7 EXCEPT copy index is
// lane&7 (was wave&3) to spread same-id lanes across 8 addresses.
// grid = (SEG_BLOCKS, NBATCH), block = 512 -> 8 iters/thread.
// ---------------------------------------------------------------------------
__global__ __launch_bounds__(SEG_THREADS) void segsum_kernel(
    const float* __restrict__ P,
    const int* __restrict__ ids,
    unsigned int* __restrict__ Spart)
{
    __shared__ unsigned int hist[NCOPY * HSTRIDE];   // ~8.2 KB
    const int b = blockIdx.y;
    const int t = threadIdx.x;

    for (int i = t; i < NCOPY * HSTRIDE; i += SEG_THREADS) hist[i] = 0u;
    __syncthreads();

    unsigned int* __restrict__ h = hist + (t & (NCOPY - 1)) * HSTRIDE;

    const float4* __restrict__ p4  = (const float4*)(P   + (size_t)b * NPIX);
    const int4*   __restrict__ id4 = (const int4*)  (ids + (size_t)b * NPIX);
    const int nvec = NPIX / 4;                      // 262144
    const int stride = gridDim.x * blockDim.x;      // 32768

    int i = blockIdx.x * blockDim.x + t;
    for (; i + (UNROLL - 1) * stride < nvec; i += UNROLL * stride) {
        float4 p[UNROLL];
        int4   d[UNROLL];
        #pragma unroll
        for (int u = 0; u < UNROLL; ++u) {          // issue all loads first
            p[u] = p4[i + u * stride];
            d[u] = id4[i + u * stride];
        }
        #pragma unroll
        for (int u = 0; u < UNROLL; ++u) {          // native ds_add_u32
            if (d[u].x >= 0) atomicAdd(&h[d[u].x], __float2uint_rn(p[u].x * SCALE));
            if (d[u].y >= 0) atomicAdd(&h[d[u].y], __float2uint_rn(p[u].y * SCALE));
            if (d[u].z >= 0) atomicAdd(&h[d[u].z], __float2uint_rn(p[u].z * SCALE));
            if (d[u].w >= 0) atomicAdd(&h[d[u].w], __float2uint_rn(p[u].w * SCALE));
        }
    }
    for (; i < nvec; i += stride) {                 // tail (empty here)
        float4 p = p4[i];
        int4   d = id4[i];
        if (d.x >= 0) atomicAdd(&h[d.x], __float2uint_rn(p.x * SCALE));
        if (d.y >= 0) atomicAdd(&h[d.y], __float2uint_rn(p.y * SCALE));
        if (d.z >= 0) atomicAdd(&h[d.z], __float2uint_rn(p.z * SCALE));
        if (d.w >= 0) atomicAdd(&h[d.w], __float2uint_rn(p.w * SCALE));
    }
    __syncthreads();

    // Per-block total <= 16384 px * 2^16 = 2^30: u32-safe across copies.
    if (t < NADMIN) {
        unsigned int s = 0u;
        #pragma unroll
        for (int c = 0; c < NCOPY; ++c) s += hist[c * HSTRIDE + t];
        Spart[((size_t)b * SEG_BLOCKS + blockIdx.x) * NADMIN + t] = s;
    }
}

// ---------------------------------------------------------------------------
// Pass 2: R[b][a] = census / (sum_blocks Spart / SCALE + eps).
// Exact u64 integer sum, fixed order; plain stores; deterministic.
// grid = NBATCH, block = NADMIN
// ---------------------------------------------------------------------------
__global__ __launch_bounds__(NADMIN) void reduce_kernel(
    const unsigned int* __restrict__ Spart,
    const float* __restrict__ census,
    float* __restrict__ R)
{
    const int b = blockIdx.x;
    const int a = threadIdx.x;
    const unsigned int* base = Spart + (size_t)b * SEG_BLOCKS * NADMIN + a;
    unsigned long long total = 0ull;
    #pragma unroll 8
    for (int j = 0; j < SEG_BLOCKS; ++j) total += base[j * NADMIN];
    float S = (float)((double)total * (1.0 / SCALE));
    R[b * NADMIN + a] = census[b * NADMIN + a] / (S + EPSILON);
}

// ---------------------------------------------------------------------------
// Pass 3: out = valid ? p * R[b][id] : p   (unchanged; passed 6 rounds)
// grid = (128, NBATCH), block = 256
// ---------------------------------------------------------------------------
__global__ __launch_bounds__(256) void apply_kernel(
    const float* __restrict__ P,
    const int* __restrict__ ids,
    const float* __restrict__ R,
    float* __restrict__ out)
{
    __shared__ float s_R[NADMIN];
    const int b = blockIdx.y;
    const int t = threadIdx.x;
    if (t < NADMIN) s_R[t] = R[b * NADMIN + t];
    __syncthreads();

    const float4* __restrict__ p4  = (const float4*)(P   + (size_t)b * NPIX);
    const int4*   __restrict__ id4 = (const int4*)  (ids + (size_t)b * NPIX);
    float4* __restrict__ o4 = (float4*)(out + (size_t)b * NPIX);
    const int nvec = NPIX / 4;
    const int stride = gridDim.x * blockDim.x;

    for (int i = blockIdx.x * blockDim.x + t; i < nvec; i += stride) {
        float4 p = p4[i];
        int4   d = id4[i];
        float4 o;
        o.x = (d.x >= 0) ? p.x * s_R[d.x] : p.x;
        o.y = (d.y >= 0) ? p.y * s_R[d.y] : p.y;
        o.z = (d.z >= 0) ? p.z * s_R[d.z] : p.z;
        o.w = (d.w >= 0) ? p.w * s_R[d.w] : p.w;
        o4[i] = o;
    }
}

extern "C" void kernel_launch(void* const* d_in, const int* in_sizes, int n_in,
                              void* d_out, int out_size, void* d_ws, size_t ws_size,
                              hipStream_t stream)
{
    const float* P      = (const float*)d_in[0];   // (B,1,H,W) f32
    const int*   ids    = (const int*)d_in[1];     // (B,H,W) i32
    const float* census = (const float*)d_in[2];   // (B,A) f32
    float* out = (float*)d_out;

    unsigned int* Spart = (unsigned int*)d_ws;                 // (B,64,A) u32 = 1 MB
    float* R = (float*)(Spart + (size_t)NBATCH * SEG_BLOCKS * NADMIN);  // (B,A)

    segsum_kernel<<<dim3(SEG_BLOCKS, NBATCH), dim3(SEG_THREADS), 0, stream>>>(P, ids, Spart);
    reduce_kernel<<<dim3(NBATCH), dim3(NADMIN), 0, stream>>>(Spart, census, R);
    apply_kernel<<<dim3(128, NBATCH), dim3(256), 0, stream>>>(P, ids, R, out);
}